// Round 17
// baseline (377.253 us; speedup 1.0000x reference)
//
#include <hip/hip_runtime.h>
#include <hip/hip_bf16.h>

typedef __bf16 bf16;
typedef __bf16 bf16x4 __attribute__((ext_vector_type(4)));
typedef __bf16 bf16x8 __attribute__((ext_vector_type(8)));
typedef float f32x4 __attribute__((ext_vector_type(4)));

#define TOK 100352   // 2048 windows * 49 tokens
#define ATT_SCALE 0.125f

#define GLOAD_LDS16(g, l)                                                        \
  __builtin_amdgcn_global_load_lds((const __attribute__((address_space(1))) void*)(g), \
                                   (__attribute__((address_space(3))) void*)(l), 16, 0, 0)

// ---------------- merged weight prep: transpose Wq|Wkv + pack Wo, one launch ----------------
// blocks 0..383: 32x32 transpose tiles (bx<16 -> Wq, else Wkv) into Wqkv_t[1536][256].
// blocks 384..447: pack Wo (f32 [512][256]) into fragment-major bf16 Wo_p.
__global__ __launch_bounds__(256) void prep_k(const float* __restrict__ Wq,
                                              const float* __restrict__ Wkv,
                                              const float* __restrict__ Wo,
                                              bf16* __restrict__ Wqkv_t,
                                              bf16* __restrict__ Wo_p) {
  int b = blockIdx.x;
  if (b < 384) {
    __shared__ float t[32][33];
    int bx = b % 48, by = b / 48;
    const float* in;
    bf16* out;
    int C, c0, r0 = by * 32;
    if (bx < 16) { in = Wq; C = 512; c0 = bx * 32; out = Wqkv_t; }
    else { in = Wkv; C = 1024; c0 = (bx - 16) * 32; out = Wqkv_t + 512 * 256; }
    int tx = threadIdx.x & 31, ty = threadIdx.x >> 5;
#pragma unroll
    for (int i = ty; i < 32; i += 8)
      t[i][tx] = in[(size_t)(r0 + i) * C + c0 + tx];
    __syncthreads();
#pragma unroll
    for (int i = ty; i < 32; i += 8)
      out[(size_t)(c0 + i) * 256 + r0 + tx] = (bf16)t[tx][i];
  } else {
    // pack Wo: frag f = ((wv*4+n)*8+h)*2+kk; lane l: row(outcol) = wv*64+n*16+(l&15),
    // col(k) = h*64+kk*32+(l>>4)*8+e
    int t = (b - 384) * 256 + threadIdx.x;  // [0, 256*64)
    int f = t >> 6, l = t & 63;
    int kk = f & 1, h = (f >> 1) & 7, n = (f >> 4) & 3, wvv = f >> 6;
    int row = wvv * 64 + n * 16 + (l & 15);
    int col = h * 64 + kk * 32 + (l >> 4) * 8;
    bf16x8 o;
#pragma unroll
    for (int e = 0; e < 8; ++e) o[e] = (bf16)Wo[(size_t)(col + e) * 256 + row];
    *(bf16x8*)(Wo_p + (size_t)f * 512 + l * 8) = o;
  }
}

// ---------------- fused partition+cast+QKV GEMM (round-9 exact: 96us/chunk measured) ----------------
// Grid (3, Tc/128): g = bn-group (g0,g1 -> Q|K, g2 -> V). A in registers (af[2][8],
// window-gathered f32->bf16). B: BK=64 double-buffered global_load_lds (source-side
// XOR swizzle, linear dest), STAGE(t+1) before compute(t), one __syncthreads/step.
// Measured local optimum: BM=256 (r15, 112us), full-K panel (r11, 110), counted-vmcnt
// (r13, 109), direct-global B (r10, 206), packed-frag B (r14, 150) all regressed.
// NEW: g=2 token-0 lanes also zero their d-rows' Vtg pad (tokens 49..63) -> the
// host-side 67MB memset is gone (validation call runs on unpoisoned ws; stale
// NaN in pad would give 0*NaN=NaN in PV, so explicit zeroing is required).
__global__ __launch_bounds__(256) void qkvg_k(const float* __restrict__ fmap,
                                              const bf16* __restrict__ Bt,
                                              bf16* __restrict__ qkv2,
                                              bf16* __restrict__ Vtg, int wbase0) {
  __shared__ bf16 Bs[2][128 * 64];
  const int tid = threadIdx.x;
  const int lane = tid & 63, wv = tid >> 6;
  const int l15 = lane & 15, l4 = lane >> 4;
  const int g = blockIdx.x;    // bn-group
  const int blk = blockIdx.y;  // token block
  bf16x8 af[2][8];
  int wl[2], tt[2];
#pragma unroll
  for (int m = 0; m < 2; ++m) {
    int tokl = blk * 128 + wv * 32 + m * 16 + l15;
    int w = tokl / 49, t = tokl - w * 49;
    wl[m] = w; tt[m] = t;
    int wg = wbase0 + w;
    int p1 = t / 7, p2 = t - p1 * 7;
    const float* ab = fmap +
        (size_t)((((wg >> 6) * 56) + ((wg >> 3) & 7) * 7 + p1) * 56 + (wg & 7) * 7 + p2) * 256;
#pragma unroll
    for (int j = 0; j < 8; ++j) {
      const float* p = ab + j * 32 + l4 * 8;
      float4 f0 = *(const float4*)p;
      float4 f1 = *(const float4*)(p + 4);
      bf16x8 o;
      o[0] = (bf16)f0.x; o[1] = (bf16)f0.y; o[2] = (bf16)f0.z; o[3] = (bf16)f0.w;
      o[4] = (bf16)f1.x; o[5] = (bf16)f1.y; o[6] = (bf16)f1.z; o[7] = (bf16)f1.w;
      af[m][j] = o;
    }
  }
  const int sg = lane >> 3;
  const int scol = ((lane & 7) ^ (sg & 7)) * 8;
#define STAGE_B(tt_, buf_)                                                                   \
  do {                                                                                       \
    int bn_ = g * 4 + ((tt_) >> 2), ks_ = (tt_) & 3;                                         \
    _Pragma("unroll") for (int i_ = 0; i_ < 4; ++i_)                                         \
        GLOAD_LDS16(Bt + (size_t)(bn_ * 128 + wv * 32 + i_ * 8 + sg) * 256 + ks_ * 64 + scol,\
                    Bs[buf_] + wv * 2048 + i_ * 512);                                        \
  } while (0)

  f32x4 acc[2][8] = {};
  STAGE_B(0, 0);
  __syncthreads();
#pragma unroll
  for (int t = 0; t < 16; ++t) {
    const int cur = t & 1, ks = t & 3;
    if (t < 15) STAGE_B(t + 1, cur ^ 1);
#pragma unroll
    for (int kk = 0; kk < 2; ++kk) {
      bf16x8 bfr[8];
#pragma unroll
      for (int n = 0; n < 8; ++n) {
        int rv = n * 16 + l15;
        bfr[n] = *(const bf16x8*)((const char*)Bs[cur] +
                 ((rv * 128 + kk * 64 + l4 * 16) ^ ((rv & 7) << 4)));
      }
#pragma unroll
      for (int m = 0; m < 2; ++m)
#pragma unroll
        for (int n = 0; n < 8; ++n)
          acc[m][n] = __builtin_amdgcn_mfma_f32_16x16x32_bf16(bfr[n], af[m][ks * 2 + kk],
                                                              acc[m][n], 0, 0, 0);
    }
    if (ks == 3) {
      const int bn = g * 4 + (t >> 2);
      if (g < 2) {  // Q|K -> qkv2[tok][1024]
#pragma unroll
        for (int m = 0; m < 2; ++m) {
          size_t row = (size_t)blk * 128 + wv * 32 + m * 16 + l15;
#pragma unroll
          for (int n = 0; n < 8; ++n) {
            bf16x4 pk;
#pragma unroll
            for (int r = 0; r < 4; ++r) pk[r] = (bf16)acc[m][n][r];
            *(bf16x4*)(qkv2 + row * 1024 + bn * 128 + n * 16 + l4 * 4) = pk;
          }
        }
      } else {  // V -> Vtg[(wl*8+h)][d][t] transposed scatter (+ pad zeroing)
#pragma unroll
        for (int m = 0; m < 2; ++m) {
#pragma unroll
          for (int n = 0; n < 8; ++n) {
            int d0 = (bn - 8) * 128 + n * 16 + l4 * 4;
            int h = d0 >> 6, dd = d0 & 63;
            size_t vb = ((size_t)wl[m] * 8 + h) * 4096 + (size_t)dd * 64 + tt[m];
#pragma unroll
            for (int r = 0; r < 4; ++r) Vtg[vb + (size_t)r * 64] = (bf16)acc[m][n][r];
          }
          if (tt[m] == 0) {  // token-0 lane owns its 4 d-rows' pad (tokens 49..63)
#pragma unroll
            for (int n = 0; n < 8; ++n) {
              int d0 = (bn - 8) * 128 + n * 16 + l4 * 4;
              int h = d0 >> 6, dd = d0 & 63;
              size_t vb0 = ((size_t)wl[m] * 8 + h) * 4096 + (size_t)dd * 64;
#pragma unroll
              for (int r = 0; r < 4; ++r)
                for (int pt = 49; pt < 64; ++pt) Vtg[vb0 + (size_t)r * 64 + pt] = (bf16)0.0f;
            }
          }
        }
      }
#pragma unroll
      for (int m = 0; m < 2; ++m)
#pragma unroll
        for (int n = 0; n < 8; ++n) acc[m][n] = (f32x4){0.f, 0.f, 0.f, 0.f};
    }
    __syncthreads();
  }
#undef STAGE_B
}

// ---------------- fused attention + out-proj (round-9 structure + packed Wo) ----------------
__global__ __launch_bounds__(256) void attn2_k(const bf16* __restrict__ qkv2,
                                               const bf16* __restrict__ Vtg,
                                               const bf16* __restrict__ Wo_p,
                                               const float* __restrict__ bias,
                                               float* __restrict__ out, int wbase) {
  __shared__ bf16 Qs[64 * 64], Ks[64 * 64], Vt[64 * 64], Ps[4 * 16 * 64], HO[64 * 64];
  const int w = blockIdx.x;
  const int tid = threadIdx.x, lane = tid & 63, wv = tid >> 6;
  const int l15 = lane & 15, l4 = lane >> 4;
  const size_t bqk = (size_t)w * 49 * 1024;
  const bf16* vbase = Vtg + (size_t)w * 8 * 4096;
  const int wg = wbase + w;
  char* pbase = (char*)Ps + wv * 2048;
  const int sr = wv * 8 + (lane >> 3);
  const int scc = ((lane & 7) ^ ((lane >> 3) & 7)) * 8;
  f32x4 acco[4][4] = {};
  for (int h = 0; h < 8; ++h) {
#pragma unroll
    for (int i = 0; i < 2; ++i) {
      GLOAD_LDS16(qkv2 + bqk + (size_t)(i * 32 + sr) * 1024 + h * 64 + scc,
                  Qs + i * 2048 + wv * 512);
      GLOAD_LDS16(qkv2 + bqk + (size_t)(i * 32 + sr) * 1024 + 512 + h * 64 + scc,
                  Ks + i * 2048 + wv * 512);
      GLOAD_LDS16(vbase + (size_t)h * 4096 + (i * 32 + sr) * 64 + scc,
                  Vt + i * 2048 + wv * 512);
    }
    __syncthreads();
    // S = Q K^T : S[q = wv*16 + l4*4+reg][k = n*16+l15]
    f32x4 s[4] = {};
#pragma unroll
    for (int kk = 0; kk < 2; ++kk) {
      int rq = wv * 16 + l15;
      bf16x8 aq = *(const bf16x8*)((const char*)Qs +
                  ((rq * 128 + kk * 64 + l4 * 16) ^ ((rq & 7) << 4)));
#pragma unroll
      for (int n = 0; n < 4; ++n) {
        int rk = n * 16 + l15;
        bf16x8 bk = *(const bf16x8*)((const char*)Ks +
                    ((rk * 128 + kk * 64 + l4 * 16) ^ ((rk & 7) << 4)));
        s[n] = __builtin_amdgcn_mfma_f32_16x16x32_bf16(aq, bk, s[n], 0, 0, 0);
      }
    }
    // masked softmax per row
    float pr[4][4];
#pragma unroll
    for (int reg = 0; reg < 4; ++reg) {
      float m = -1e30f;
#pragma unroll
      for (int n = 0; n < 4; ++n) {
        float v = s[n][reg] * ATT_SCALE;
        if (n * 16 + l15 < 49) m = fmaxf(m, v);
      }
#pragma unroll
      for (int d = 1; d < 16; d <<= 1) m = fmaxf(m, __shfl_xor(m, d));
      float sum = 0.f;
#pragma unroll
      for (int n = 0; n < 4; ++n) {
        float p = (n * 16 + l15 < 49) ? __expf(s[n][reg] * ATT_SCALE - m) : 0.f;
        pr[n][reg] = p;
        sum += p;
      }
#pragma unroll
      for (int d = 1; d < 16; d <<= 1) sum += __shfl_xor(sum, d);
      float inv = 1.f / sum;
#pragma unroll
      for (int n = 0; n < 4; ++n) pr[n][reg] *= inv;
    }
    // P -> wave-private LDS (swizzled)
#pragma unroll
    for (int n = 0; n < 4; ++n)
#pragma unroll
      for (int reg = 0; reg < 4; ++reg) {
        int rl = l4 * 4 + reg, col = n * 16 + l15;
        int off = ((rl * 64 + col) * 2) ^ ((rl & 7) << 4);
        *(bf16*)(pbase + off) = (bf16)pr[n][reg];
      }
    // PV (swapped): o token = wv*16+l15, chan = n*16 + l4*4+reg
    f32x4 o[4] = {};
#pragma unroll
    for (int kk = 0; kk < 2; ++kk) {
      int rp = l15;
      bf16x8 ap = *(const bf16x8*)(pbase +
                  ((rp * 128 + kk * 64 + l4 * 16) ^ ((rp & 7) << 4)));
#pragma unroll
      for (int n = 0; n < 4; ++n) {
        int rv = n * 16 + l15;
        bf16x8 bv = *(const bf16x8*)((const char*)Vt +
                    ((rv * 128 + kk * 64 + l4 * 16) ^ ((rv & 7) << 4)));
        o[n] = __builtin_amdgcn_mfma_f32_16x16x32_bf16(bv, ap, o[n], 0, 0, 0);
      }
    }
    // head-out -> LDS [64 tok][64 chan], granule row-XOR swizzle
    {
      int hrow = wv * 16 + l15;
#pragma unroll
      for (int n = 0; n < 4; ++n) {
        bf16x4 pk;
#pragma unroll
        for (int r = 0; r < 4; ++r) pk[r] = (bf16)o[n][r];
        int off = (hrow * 128 + n * 32 + l4 * 8) ^ ((hrow & 7) << 4);
        *(bf16x4*)((char*)HO + off) = pk;
      }
    }
    __syncthreads();
    // out-proj: acco[m][n] += HO @ Wo_h^T, Wo frags from packed panel (coalesced)
#pragma unroll
    for (int kk = 0; kk < 2; ++kk) {
      bf16x8 af[4];
#pragma unroll
      for (int m = 0; m < 4; ++m) {
        int r = m * 16 + l15;
        af[m] = *(const bf16x8*)((const char*)HO +
                 ((r * 128 + kk * 64 + l4 * 16) ^ ((r & 7) << 4)));
      }
#pragma unroll
      for (int n = 0; n < 4; ++n) {
        int f = ((wv * 4 + n) * 8 + h) * 2 + kk;
        bf16x8 bv = *(const bf16x8*)(Wo_p + (size_t)f * 512 + lane * 8);
#pragma unroll
        for (int m = 0; m < 4; ++m)
          acco[m][n] = __builtin_amdgcn_mfma_f32_16x16x32_bf16(bv, af[m], acco[m][n], 0, 0, 0);
      }
    }
  }
  // epilogue: scatter f32 + bias
  int bb = wg >> 6, xx = (wg >> 3) & 7, yy = wg & 7;
#pragma unroll
  for (int m = 0; m < 4; ++m) {
    int rl = m * 16 + l15;
    if (rl < 49) {
      int p1 = rl / 7, p2 = rl - p1 * 7;
      size_t orow = (size_t)(bb * 56 + xx * 7 + p1) * 56 + yy * 7 + p2;
      float* op = out + orow * 256 + wv * 64;
#pragma unroll
      for (int n = 0; n < 4; ++n) {
        int col = n * 16 + l4 * 4;
        float4 b4 = *(const float4*)(bias + wv * 64 + col);
        float4 v;
        v.x = acco[m][n][0] + b4.x;
        v.y = acco[m][n][1] + b4.y;
        v.z = acco[m][n][2] + b4.z;
        v.w = acco[m][n][3] + b4.w;
        *(float4*)(op + col) = v;
      }
    }
  }
}

extern "C" void kernel_launch(void* const* d_in, const int* in_sizes, int n_in,
                              void* d_out, int out_size, void* d_ws, size_t ws_size,
                              hipStream_t stream) {
  const float* fmap = (const float*)d_in[0];
  const float* Wq = (const float*)d_in[1];
  const float* Wkv = (const float*)d_in[2];
  const float* Wo = (const float*)d_in[3];
  const float* bo = (const float*)d_in[4];
  float* out = (float*)d_out;
  char* ws = (char*)d_ws;

  const size_t WQKV_B = 1536ull * 256 * 2;  // 786,432
  const size_t WOP_B = 256ull * 512 * 2;    // 262,144 (packed)
  const size_t wbytes = WQKV_B + WOP_B;     // 1 MB

  // per-chunk: Vtg = (Tc/49)*64KB, qkv2 = Tc*2048 B, + 64KB margin. nc=2 keeps chunk
  // intermediates (169MB) L3-resident between producer and consumer.
  int nc = 0;
  size_t Tc = 0, VtgB = 0;
  for (int c = 2; c <= 16; c <<= 1) {
    size_t tc = TOK / c;  // multiple of 6272 = 49*128
    size_t vb = (tc / 49) * 65536ull;
    if (wbytes + vb + tc * 2048ull + 65536ull <= ws_size) { nc = c; Tc = tc; VtgB = vb; break; }
  }
  if (nc == 0) return;

  bf16* Wqkv_t = (bf16*)(ws);
  bf16* Wo_p = (bf16*)(ws + WQKV_B);
  bf16* Vtg = (bf16*)(ws + wbytes);
  bf16* qkv2 = (bf16*)(ws + wbytes + VtgB);

  hipLaunchKernelGGL(prep_k, dim3(448), dim3(256), 0, stream, Wq, Wkv, Wo, Wqkv_t, Wo_p);

  for (int c = 0; c < nc; ++c) {
    int tok0 = (int)(c * Tc);
    int wloc = (int)(Tc / 49);
    hipLaunchKernelGGL(qkvg_k, dim3(3, (int)(Tc / 128)), dim3(256), 0, stream, fmap, Wqkv_t,
                       qkv2, Vtg, tok0 / 49);
    hipLaunchKernelGGL(attn2_k, dim3(wloc), dim3(256), 0, stream, qkv2, Vtg, Wo_p, bo, out,
                       tok0 / 49);
  }
}

// Round 18
// 323.082 us; speedup vs baseline: 1.1677x; 1.1677x over previous
//
#include <hip/hip_runtime.h>
#include <hip/hip_bf16.h>

typedef __bf16 bf16;
typedef __bf16 bf16x4 __attribute__((ext_vector_type(4)));
typedef __bf16 bf16x8 __attribute__((ext_vector_type(8)));
typedef float f32x4 __attribute__((ext_vector_type(4)));

#define TOK 100352   // 2048 windows * 49 tokens
#define ATT_SCALE 0.125f

#define GLOAD_LDS16(g, l)                                                        \
  __builtin_amdgcn_global_load_lds((const __attribute__((address_space(1))) void*)(g), \
                                   (__attribute__((address_space(3))) void*)(l), 16, 0, 0)

// ---------------- merged weight prep: transpose Wq|Wkv + pack Wo, one launch ----------------
__global__ __launch_bounds__(256) void prep_k(const float* __restrict__ Wq,
                                              const float* __restrict__ Wkv,
                                              const float* __restrict__ Wo,
                                              bf16* __restrict__ Wqkv_t,
                                              bf16* __restrict__ Wo_p) {
  int b = blockIdx.x;
  if (b < 384) {
    __shared__ float t[32][33];
    int bx = b % 48, by = b / 48;
    const float* in;
    bf16* out;
    int C, c0, r0 = by * 32;
    if (bx < 16) { in = Wq; C = 512; c0 = bx * 32; out = Wqkv_t; }
    else { in = Wkv; C = 1024; c0 = (bx - 16) * 32; out = Wqkv_t + 512 * 256; }
    int tx = threadIdx.x & 31, ty = threadIdx.x >> 5;
#pragma unroll
    for (int i = ty; i < 32; i += 8)
      t[i][tx] = in[(size_t)(r0 + i) * C + c0 + tx];
    __syncthreads();
#pragma unroll
    for (int i = ty; i < 32; i += 8)
      out[(size_t)(c0 + i) * 256 + r0 + tx] = (bf16)t[tx][i];
  } else {
    // pack Wo: frag f = ((wv*4+n)*8+h)*2+kk; lane l: row(outcol) = wv*64+n*16+(l&15),
    // col(k) = h*64+kk*32+(l>>4)*8+e
    int t = (b - 384) * 256 + threadIdx.x;  // [0, 256*64)
    int f = t >> 6, l = t & 63;
    int kk = f & 1, h = (f >> 1) & 7, n = (f >> 4) & 3, wvv = f >> 6;
    int row = wvv * 64 + n * 16 + (l & 15);
    int col = h * 64 + kk * 32 + (l >> 4) * 8;
    bf16x8 o;
#pragma unroll
    for (int e = 0; e < 8; ++e) o[e] = (bf16)Wo[(size_t)(col + e) * 256 + row];
    *(bf16x8*)(Wo_p + (size_t)f * 512 + l * 8) = o;
  }
}

// ---------------- pad-only Vtg zero: tokens 48..63 of every d-row (32B aligned store) ----------
// qkvg writes tokens 0..48 (48 overwritten after us); pads 49..63 are never written by
// qkvg and Vtg is reused across chunks -> zero ONCE before the chunk loop. Replaces the
// 67MB full-buffer memset with 33.5MB coalesced stores.
__global__ __launch_bounds__(256) void padzero_k(bf16* __restrict__ Vtg, int nwh) {
  int t = blockIdx.x * 256 + threadIdx.x;  // one thread per (w*8+h, dd)
  int wh = t >> 6, dd = t & 63;
  if (wh < nwh) {
    uint4 z = {0, 0, 0, 0};
    char* p = (char*)(Vtg + (size_t)wh * 4096 + dd * 64 + 48);
    *(uint4*)p = z;
    *(uint4*)(p + 16) = z;
  }
}

// ---------------- fused partition+cast+QKV GEMM (round-9/16 exact: 96us/chunk measured) --------
// Grid (3, Tc/128): g = bn-group (g0,g1 -> Q|K, g2 -> V). A in registers (af[2][8],
// window-gathered f32->bf16). B: BK=64 double-buffered global_load_lds (source-side
// XOR swizzle, linear dest), STAGE(t+1) before compute(t), one __syncthreads/step.
// VGPR 124 — LEAVE THE EPILOGUE ALONE: r17's fused pad-zero pushed 124->132 VGPR,
// crossing the 128 occupancy cliff (17%->9.7%, 96->130us).
__global__ __launch_bounds__(256) void qkvg_k(const float* __restrict__ fmap,
                                              const bf16* __restrict__ Bt,
                                              bf16* __restrict__ qkv2,
                                              bf16* __restrict__ Vtg, int wbase0) {
  __shared__ bf16 Bs[2][128 * 64];
  const int tid = threadIdx.x;
  const int lane = tid & 63, wv = tid >> 6;
  const int l15 = lane & 15, l4 = lane >> 4;
  const int g = blockIdx.x;    // bn-group
  const int blk = blockIdx.y;  // token block
  bf16x8 af[2][8];
  int wl[2], tt[2];
#pragma unroll
  for (int m = 0; m < 2; ++m) {
    int tokl = blk * 128 + wv * 32 + m * 16 + l15;
    int w = tokl / 49, t = tokl - w * 49;
    wl[m] = w; tt[m] = t;
    int wg = wbase0 + w;
    int p1 = t / 7, p2 = t - p1 * 7;
    const float* ab = fmap +
        (size_t)((((wg >> 6) * 56) + ((wg >> 3) & 7) * 7 + p1) * 56 + (wg & 7) * 7 + p2) * 256;
#pragma unroll
    for (int j = 0; j < 8; ++j) {
      const float* p = ab + j * 32 + l4 * 8;
      float4 f0 = *(const float4*)p;
      float4 f1 = *(const float4*)(p + 4);
      bf16x8 o;
      o[0] = (bf16)f0.x; o[1] = (bf16)f0.y; o[2] = (bf16)f0.z; o[3] = (bf16)f0.w;
      o[4] = (bf16)f1.x; o[5] = (bf16)f1.y; o[6] = (bf16)f1.z; o[7] = (bf16)f1.w;
      af[m][j] = o;
    }
  }
  const int sg = lane >> 3;
  const int scol = ((lane & 7) ^ (sg & 7)) * 8;
#define STAGE_B(tt_, buf_)                                                                   \
  do {                                                                                       \
    int bn_ = g * 4 + ((tt_) >> 2), ks_ = (tt_) & 3;                                         \
    _Pragma("unroll") for (int i_ = 0; i_ < 4; ++i_)                                         \
        GLOAD_LDS16(Bt + (size_t)(bn_ * 128 + wv * 32 + i_ * 8 + sg) * 256 + ks_ * 64 + scol,\
                    Bs[buf_] + wv * 2048 + i_ * 512);                                        \
  } while (0)

  f32x4 acc[2][8] = {};
  STAGE_B(0, 0);
  __syncthreads();
#pragma unroll
  for (int t = 0; t < 16; ++t) {
    const int cur = t & 1, ks = t & 3;
    if (t < 15) STAGE_B(t + 1, cur ^ 1);
#pragma unroll
    for (int kk = 0; kk < 2; ++kk) {
      bf16x8 bfr[8];
#pragma unroll
      for (int n = 0; n < 8; ++n) {
        int rv = n * 16 + l15;
        bfr[n] = *(const bf16x8*)((const char*)Bs[cur] +
                 ((rv * 128 + kk * 64 + l4 * 16) ^ ((rv & 7) << 4)));
      }
#pragma unroll
      for (int m = 0; m < 2; ++m)
#pragma unroll
        for (int n = 0; n < 8; ++n)
          acc[m][n] = __builtin_amdgcn_mfma_f32_16x16x32_bf16(bfr[n], af[m][ks * 2 + kk],
                                                              acc[m][n], 0, 0, 0);
    }
    if (ks == 3) {
      const int bn = g * 4 + (t >> 2);
      if (g < 2) {  // Q|K -> qkv2[tok][1024]
#pragma unroll
        for (int m = 0; m < 2; ++m) {
          size_t row = (size_t)blk * 128 + wv * 32 + m * 16 + l15;
#pragma unroll
          for (int n = 0; n < 8; ++n) {
            bf16x4 pk;
#pragma unroll
            for (int r = 0; r < 4; ++r) pk[r] = (bf16)acc[m][n][r];
            *(bf16x4*)(qkv2 + row * 1024 + bn * 128 + n * 16 + l4 * 4) = pk;
          }
        }
      } else {  // V -> Vtg[(wl*8+h)][d][t] transposed scatter
#pragma unroll
        for (int m = 0; m < 2; ++m) {
#pragma unroll
          for (int n = 0; n < 8; ++n) {
            int d0 = (bn - 8) * 128 + n * 16 + l4 * 4;
            int h = d0 >> 6, dd = d0 & 63;
            size_t vb = ((size_t)wl[m] * 8 + h) * 4096 + (size_t)dd * 64 + tt[m];
#pragma unroll
            for (int r = 0; r < 4; ++r) Vtg[vb + (size_t)r * 64] = (bf16)acc[m][n][r];
          }
        }
      }
#pragma unroll
      for (int m = 0; m < 2; ++m)
#pragma unroll
        for (int n = 0; n < 8; ++n) acc[m][n] = (f32x4){0.f, 0.f, 0.f, 0.f};
    }
    __syncthreads();
  }
#undef STAGE_B
}

// ---------------- fused attention + out-proj (round-16 exact: packed Wo) ----------------
__global__ __launch_bounds__(256) void attn2_k(const bf16* __restrict__ qkv2,
                                               const bf16* __restrict__ Vtg,
                                               const bf16* __restrict__ Wo_p,
                                               const float* __restrict__ bias,
                                               float* __restrict__ out, int wbase) {
  __shared__ bf16 Qs[64 * 64], Ks[64 * 64], Vt[64 * 64], Ps[4 * 16 * 64], HO[64 * 64];
  const int w = blockIdx.x;
  const int tid = threadIdx.x, lane = tid & 63, wv = tid >> 6;
  const int l15 = lane & 15, l4 = lane >> 4;
  const size_t bqk = (size_t)w * 49 * 1024;
  const bf16* vbase = Vtg + (size_t)w * 8 * 4096;
  const int wg = wbase + w;
  char* pbase = (char*)Ps + wv * 2048;
  const int sr = wv * 8 + (lane >> 3);
  const int scc = ((lane & 7) ^ ((lane >> 3) & 7)) * 8;
  f32x4 acco[4][4] = {};
  for (int h = 0; h < 8; ++h) {
#pragma unroll
    for (int i = 0; i < 2; ++i) {
      GLOAD_LDS16(qkv2 + bqk + (size_t)(i * 32 + sr) * 1024 + h * 64 + scc,
                  Qs + i * 2048 + wv * 512);
      GLOAD_LDS16(qkv2 + bqk + (size_t)(i * 32 + sr) * 1024 + 512 + h * 64 + scc,
                  Ks + i * 2048 + wv * 512);
      GLOAD_LDS16(vbase + (size_t)h * 4096 + (i * 32 + sr) * 64 + scc,
                  Vt + i * 2048 + wv * 512);
    }
    __syncthreads();
    // S = Q K^T : S[q = wv*16 + l4*4+reg][k = n*16+l15]
    f32x4 s[4] = {};
#pragma unroll
    for (int kk = 0; kk < 2; ++kk) {
      int rq = wv * 16 + l15;
      bf16x8 aq = *(const bf16x8*)((const char*)Qs +
                  ((rq * 128 + kk * 64 + l4 * 16) ^ ((rq & 7) << 4)));
#pragma unroll
      for (int n = 0; n < 4; ++n) {
        int rk = n * 16 + l15;
        bf16x8 bk = *(const bf16x8*)((const char*)Ks +
                    ((rk * 128 + kk * 64 + l4 * 16) ^ ((rk & 7) << 4)));
        s[n] = __builtin_amdgcn_mfma_f32_16x16x32_bf16(aq, bk, s[n], 0, 0, 0);
      }
    }
    // masked softmax per row
    float pr[4][4];
#pragma unroll
    for (int reg = 0; reg < 4; ++reg) {
      float m = -1e30f;
#pragma unroll
      for (int n = 0; n < 4; ++n) {
        float v = s[n][reg] * ATT_SCALE;
        if (n * 16 + l15 < 49) m = fmaxf(m, v);
      }
#pragma unroll
      for (int d = 1; d < 16; d <<= 1) m = fmaxf(m, __shfl_xor(m, d));
      float sum = 0.f;
#pragma unroll
      for (int n = 0; n < 4; ++n) {
        float p = (n * 16 + l15 < 49) ? __expf(s[n][reg] * ATT_SCALE - m) : 0.f;
        pr[n][reg] = p;
        sum += p;
      }
#pragma unroll
      for (int d = 1; d < 16; d <<= 1) sum += __shfl_xor(sum, d);
      float inv = 1.f / sum;
#pragma unroll
      for (int n = 0; n < 4; ++n) pr[n][reg] *= inv;
    }
    // P -> wave-private LDS (swizzled)
#pragma unroll
    for (int n = 0; n < 4; ++n)
#pragma unroll
      for (int reg = 0; reg < 4; ++reg) {
        int rl = l4 * 4 + reg, col = n * 16 + l15;
        int off = ((rl * 64 + col) * 2) ^ ((rl & 7) << 4);
        *(bf16*)(pbase + off) = (bf16)pr[n][reg];
      }
    // PV (swapped): o token = wv*16+l15, chan = n*16 + l4*4+reg
    f32x4 o[4] = {};
#pragma unroll
    for (int kk = 0; kk < 2; ++kk) {
      int rp = l15;
      bf16x8 ap = *(const bf16x8*)(pbase +
                  ((rp * 128 + kk * 64 + l4 * 16) ^ ((rp & 7) << 4)));
#pragma unroll
      for (int n = 0; n < 4; ++n) {
        int rv = n * 16 + l15;
        bf16x8 bv = *(const bf16x8*)((const char*)Vt +
                    ((rv * 128 + kk * 64 + l4 * 16) ^ ((rv & 7) << 4)));
        o[n] = __builtin_amdgcn_mfma_f32_16x16x32_bf16(bv, ap, o[n], 0, 0, 0);
      }
    }
    // head-out -> LDS [64 tok][64 chan], granule row-XOR swizzle
    {
      int hrow = wv * 16 + l15;
#pragma unroll
      for (int n = 0; n < 4; ++n) {
        bf16x4 pk;
#pragma unroll
        for (int r = 0; r < 4; ++r) pk[r] = (bf16)o[n][r];
        int off = (hrow * 128 + n * 32 + l4 * 8) ^ ((hrow & 7) << 4);
        *(bf16x4*)((char*)HO + off) = pk;
      }
    }
    __syncthreads();
    // out-proj: acco[m][n] += HO @ Wo_h^T, Wo frags from packed panel (coalesced)
#pragma unroll
    for (int kk = 0; kk < 2; ++kk) {
      bf16x8 af[4];
#pragma unroll
      for (int m = 0; m < 4; ++m) {
        int r = m * 16 + l15;
        af[m] = *(const bf16x8*)((const char*)HO +
                 ((r * 128 + kk * 64 + l4 * 16) ^ ((r & 7) << 4)));
      }
#pragma unroll
      for (int n = 0; n < 4; ++n) {
        int f = ((wv * 4 + n) * 8 + h) * 2 + kk;
        bf16x8 bv = *(const bf16x8*)(Wo_p + (size_t)f * 512 + lane * 8);
#pragma unroll
        for (int m = 0; m < 4; ++m)
          acco[m][n] = __builtin_amdgcn_mfma_f32_16x16x32_bf16(bv, af[m], acco[m][n], 0, 0, 0);
      }
    }
  }
  // epilogue: scatter f32 + bias
  int bb = wg >> 6, xx = (wg >> 3) & 7, yy = wg & 7;
#pragma unroll
  for (int m = 0; m < 4; ++m) {
    int rl = m * 16 + l15;
    if (rl < 49) {
      int p1 = rl / 7, p2 = rl - p1 * 7;
      size_t orow = (size_t)(bb * 56 + xx * 7 + p1) * 56 + yy * 7 + p2;
      float* op = out + orow * 256 + wv * 64;
#pragma unroll
      for (int n = 0; n < 4; ++n) {
        int col = n * 16 + l4 * 4;
        float4 b4 = *(const float4*)(bias + wv * 64 + col);
        float4 v;
        v.x = acco[m][n][0] + b4.x;
        v.y = acco[m][n][1] + b4.y;
        v.z = acco[m][n][2] + b4.z;
        v.w = acco[m][n][3] + b4.w;
        *(float4*)(op + col) = v;
      }
    }
  }
}

extern "C" void kernel_launch(void* const* d_in, const int* in_sizes, int n_in,
                              void* d_out, int out_size, void* d_ws, size_t ws_size,
                              hipStream_t stream) {
  const float* fmap = (const float*)d_in[0];
  const float* Wq = (const float*)d_in[1];
  const float* Wkv = (const float*)d_in[2];
  const float* Wo = (const float*)d_in[3];
  const float* bo = (const float*)d_in[4];
  float* out = (float*)d_out;
  char* ws = (char*)d_ws;

  const size_t WQKV_B = 1536ull * 256 * 2;  // 786,432
  const size_t WOP_B = 256ull * 512 * 2;    // 262,144 (packed)
  const size_t wbytes = WQKV_B + WOP_B;     // 1 MB

  // per-chunk: Vtg = (Tc/49)*64KB, qkv2 = Tc*2048 B, + 64KB margin. nc=2 keeps chunk
  // intermediates (169MB) L3-resident between producer and consumer.
  int nc = 0;
  size_t Tc = 0, VtgB = 0;
  for (int c = 2; c <= 16; c <<= 1) {
    size_t tc = TOK / c;  // multiple of 6272 = 49*128
    size_t vb = (tc / 49) * 65536ull;
    if (wbytes + vb + tc * 2048ull + 65536ull <= ws_size) { nc = c; Tc = tc; VtgB = vb; break; }
  }
  if (nc == 0) return;

  bf16* Wqkv_t = (bf16*)(ws);
  bf16* Wo_p = (bf16*)(ws + WQKV_B);
  bf16* Vtg = (bf16*)(ws + wbytes);
  bf16* qkv2 = (bf16*)(ws + wbytes + VtgB);

  hipLaunchKernelGGL(prep_k, dim3(448), dim3(256), 0, stream, Wq, Wkv, Wo, Wqkv_t, Wo_p);
  // zero Vtg pad region once (qkvg only writes tokens 0..48; pads persist across chunks)
  int nwh = (int)(Tc / 49) * 8;
  hipLaunchKernelGGL(padzero_k, dim3((nwh * 64 + 255) / 256), dim3(256), 0, stream, Vtg, nwh);

  for (int c = 0; c < nc; ++c) {
    int tok0 = (int)(c * Tc);
    int wloc = (int)(Tc / 49);
    hipLaunchKernelGGL(qkvg_k, dim3(3, (int)(Tc / 128)), dim3(256), 0, stream, fmap, Wqkv_t,
                       qkv2, Vtg, tok0 / 49);
    hipLaunchKernelGGL(attn2_k, dim3(wloc), dim3(256), 0, stream, qkv2, Vtg, Wo_p, bo, out,
                       tok0 / 49);
  }
}